// Round 2
// baseline (203.352 us; speedup 1.0000x reference)
//
#include <hip/hip_runtime.h>
#include <stdint.h>

using bf16x8_t = __attribute__((ext_vector_type(8))) __bf16;
using f32x4_t  = __attribute__((ext_vector_type(4))) float;
using u16x8_t  = __attribute__((ext_vector_type(8))) unsigned short;

#define KD 2048   // hidden dim

static __device__ __forceinline__ unsigned short f2bf(float f) {
  union { float f; unsigned u; } v; v.f = f;
  unsigned r = v.u + 0x7fffu + ((v.u >> 16) & 1u);   // RNE
  return (unsigned short)(r >> 16);
}

// ---- zero wsum (8 KB) ----
__global__ void k_zero(float* __restrict__ w) {
  w[blockIdx.x * 256 + threadIdx.x] = 0.f;
}

// ---- fused prep: blocks 0..127 accumulate wsum partials (atomicAdd);
//      blocks 128..255 pack W into pre-fragmented bf16 layout ----
// wbf2 layout: elem ((s*8+nf)*64 + lane)*8 + j  <->  B[col=nf*16+(lane&15)][k=s*32+(lane>>4)*8+j]
// cols 0..63 = w_a rows, cols 64..127 = w_b rows.
__global__ void k_prep(const float* __restrict__ wqkv, const float* __restrict__ wz,
                       const float* __restrict__ wb, const float* __restrict__ wa,
                       float* __restrict__ wsum, unsigned short* __restrict__ wbf2) {
  const int bid = blockIdx.x, t = threadIdx.x;
  if (bid < 128) {
    float p[8] = {0.f, 0.f, 0.f, 0.f, 0.f, 0.f, 0.f, 0.f};
    #pragma unroll
    for (int dd = 0; dd < 10; ++dd) {
      const int d = bid * 10 + dd;                       // 0..1279
      const float* row = (d < 768) ? (wqkv + (size_t)d * KD)
                                   : (wz + (size_t)(d - 768) * KD);
      #pragma unroll
      for (int j = 0; j < 8; ++j) p[j] += row[t + 256 * j];
    }
    #pragma unroll
    for (int j = 0; j < 8; ++j) atomicAdd(&wsum[t + 256 * j], p[j]);
  } else {
    const int u = (bid - 128) * 256 + t;                 // (s,nf,lane) triple
    const int l = u & 63;
    const int nf = (u >> 6) & 7;
    const int s = u >> 9;
    const int c = nf * 16 + (l & 15);                    // output column 0..127
    const int k = s * 32 + ((l >> 4) << 3);
    const float* src = (c < 64) ? (wa + (size_t)c * KD + k)
                                : (wb + (size_t)(c - 64) * KD + k);
    f32x4_t v0 = *(const f32x4_t*)(src);
    f32x4_t v1 = *(const f32x4_t*)(src + 4);
    u16x8_t o;
    o[0] = f2bf(v0[0]); o[1] = f2bf(v0[1]); o[2] = f2bf(v0[2]); o[3] = f2bf(v0[3]);
    o[4] = f2bf(v1[0]); o[5] = f2bf(v1[1]); o[6] = f2bf(v1[2]); o[7] = f2bf(v1[3]);
    *(u16x8_t*)(wbf2 + (size_t)u * 8) = o;
  }
}

// ---- main: no LDS, no barriers. 4 waves/block, wave owns 16 rows x 128 cols.
// A-frag loaded straight from global x (fp32->bf16 in regs); B-frags from
// pre-fragmented wbf2 (L1/L2-resident, lane-contiguous); s0 = fp32 dot(x,wsum).
__global__ __launch_bounds__(256, 2) void k_main(
    const float* __restrict__ x, const float* __restrict__ wsum,
    const unsigned short* __restrict__ wbf2, float* __restrict__ out)
{
  const int t = threadIdx.x;
  const int lane = t & 63;
  const int wv = t >> 6;
  const int g = lane >> 4;        // k-group 0..3
  const int r15 = lane & 15;      // row-within-wave / col-within-frag
  const size_t tile = (size_t)blockIdx.x * 64;

  const float* xrow = x + (tile + wv * 16 + r15) * KD + g * 8;
  const float* wsp  = wsum + g * 8;
  const unsigned short* wp = wbf2 + (size_t)lane * 8;

  f32x4_t acc[8];
  #pragma unroll
  for (int i = 0; i < 8; ++i) acc[i] = f32x4_t{0.f, 0.f, 0.f, 0.f};
  float s0 = 0.f;

  for (int s = 0; s < 64; ++s) {
    f32x4_t x0 = *(const f32x4_t*)(xrow + s * 32);
    f32x4_t x1 = *(const f32x4_t*)(xrow + s * 32 + 4);
    f32x4_t w0 = *(const f32x4_t*)(wsp + s * 32);
    f32x4_t w1 = *(const f32x4_t*)(wsp + s * 32 + 4);

    union { u16x8_t u; bf16x8_t b; } af;
    af.u[0] = f2bf(x0[0]); af.u[1] = f2bf(x0[1]); af.u[2] = f2bf(x0[2]); af.u[3] = f2bf(x0[3]);
    af.u[4] = f2bf(x1[0]); af.u[5] = f2bf(x1[1]); af.u[6] = f2bf(x1[2]); af.u[7] = f2bf(x1[3]);

    s0 += x0[0] * w0[0] + x0[1] * w0[1] + x0[2] * w0[2] + x0[3] * w0[3]
        + x1[0] * w1[0] + x1[1] * w1[1] + x1[2] * w1[2] + x1[3] * w1[3];

    #pragma unroll
    for (int nf = 0; nf < 8; ++nf) {
      bf16x8_t bfr = *(const bf16x8_t*)(wp + (size_t)(s * 8 + nf) * 512);
      acc[nf] = __builtin_amdgcn_mfma_f32_16x16x32_bf16(af.b, bfr, acc[nf], 0, 0, 0);
    }
  }

  // s0: combine the 4 k-groups of each row (lanes differing in bits 4,5)
  s0 += __shfl_xor(s0, 16, 64);
  s0 += __shfl_xor(s0, 32, 64);
  // now every lane holds full s0 for row r15 of this wave's tile

  // epilogue: C col = lane&15, row = g*4 + reg. Pair a-frag nf with b-frag nf+4.
  #pragma unroll
  for (int r = 0; r < 4; ++r) {
    float v = 0.f;
    #pragma unroll
    for (int nf = 0; nf < 4; ++nf) {
      float av = acc[nf][r];
      float bv = acc[nf + 4][r];
      v += av / (1.f + __expf(-bv));          // a * sigmoid(b)
    }
    v += __shfl_xor(v, 1, 64);
    v += __shfl_xor(v, 2, 64);
    v += __shfl_xor(v, 4, 64);
    v += __shfl_xor(v, 8, 64);
    const int row = g * 4 + r;                // 0..15
    float s0r = __shfl(s0, row, 64);          // s0 lives at lane whose r15 == row
    if (r15 == 0) out[tile + wv * 16 + row] = v + s0r;
  }
}

extern "C" void kernel_launch(void* const* d_in, const int* in_sizes, int n_in,
                              void* d_out, int out_size, void* d_ws, size_t ws_size,
                              hipStream_t stream) {
  const float* x    = (const float*)d_in[0];
  const float* wqkv = (const float*)d_in[1];
  const float* wz   = (const float*)d_in[2];
  const float* wb   = (const float*)d_in[3];   // dict order: w_b before w_a
  const float* wa   = (const float*)d_in[4];
  float* out = (float*)d_out;

  float* wsum = (float*)d_ws;                                   // 2048 f32 (8 KB)
  unsigned short* wbf2 = (unsigned short*)((char*)d_ws + 8192); // 512 KB pre-fragmented W

  k_zero<<<8, 256, 0, stream>>>(wsum);
  k_prep<<<256, 256, 0, stream>>>(wqkv, wz, wb, wa, wsum, wbf2);
  k_main<<<out_size / 64, 256, 0, stream>>>(x, wsum, wbf2, out);
}

// Round 3
// 88.731 us; speedup vs baseline: 2.2918x; 2.2918x over previous
//
#include <hip/hip_runtime.h>
#include <stdint.h>

using bf16x8_t = __attribute__((ext_vector_type(8))) __bf16;
using f32x4_t  = __attribute__((ext_vector_type(4))) float;
using u16x8_t  = __attribute__((ext_vector_type(8))) unsigned short;

#define KD 2048

static __device__ __forceinline__ unsigned short f2bf(float f) {
  union { float f; unsigned u; } v; v.f = f;
  unsigned r = v.u + 0x7fffu + ((v.u >> 16) & 1u);   // RNE
  return (unsigned short)(r >> 16);
}

// ---- prep1: partial[b][h] = sum over 10 W-rows (qkv||z), deterministic ----
__global__ void k_prep1(const float* __restrict__ wqkv, const float* __restrict__ wz,
                        float* __restrict__ partial) {
  const int b = blockIdx.x, t = threadIdx.x;     // 128 blocks x 256 thr
  float p[8] = {0.f,0.f,0.f,0.f,0.f,0.f,0.f,0.f};
  #pragma unroll
  for (int dd = 0; dd < 10; ++dd) {
    const int d = b * 10 + dd;                   // 0..1279
    const float* row = (d < 768) ? (wqkv + (size_t)d * KD)
                                 : (wz + (size_t)(d - 768) * KD);
    #pragma unroll
    for (int j = 0; j < 8; ++j) p[j] += row[t + 256 * j];
  }
  #pragma unroll
  for (int j = 0; j < 8; ++j) partial[(size_t)b * KD + t + 256 * j] = p[j];
}

// ---- prep2: pack 9-fragment bf16 W. Layout: elem ((s*9+nf)*64+lane)*8+j  <->
//  B[col = nf*16+(lane&15)][k = s*32+(lane>>4)*8+j]; cols 0..63 = w_a rows,
//  64..127 = w_b rows, col 128 = wsum (from partial), cols 129..143 = 0. ----
__global__ void k_prep2(const float* __restrict__ wb, const float* __restrict__ wa,
                        const float* __restrict__ partial, unsigned short* __restrict__ wbf3) {
  const int u = blockIdx.x * 256 + threadIdx.x;  // 144 blocks -> 36864 threads
  const int l = u & 63;
  const int vv = u >> 6;
  const int nf = vv % 9;
  const int s  = vv / 9;
  const int k  = s * 32 + ((l >> 4) << 3);
  u16x8_t o;
  if (nf < 8) {
    const int c = nf * 16 + (l & 15);
    const float* src = (c < 64) ? (wa + (size_t)c * KD + k)
                                : (wb + (size_t)(c - 64) * KD + k);
    f32x4_t v0 = *(const f32x4_t*)(src);
    f32x4_t v1 = *(const f32x4_t*)(src + 4);
    o[0]=f2bf(v0[0]); o[1]=f2bf(v0[1]); o[2]=f2bf(v0[2]); o[3]=f2bf(v0[3]);
    o[4]=f2bf(v1[0]); o[5]=f2bf(v1[1]); o[6]=f2bf(v1[2]); o[7]=f2bf(v1[3]);
  } else if ((l & 15) == 0) {
    f32x4_t s0 = {0.f,0.f,0.f,0.f}, s1 = {0.f,0.f,0.f,0.f};
    for (int p = 0; p < 128; ++p) {
      s0 += *(const f32x4_t*)(partial + (size_t)p * KD + k);
      s1 += *(const f32x4_t*)(partial + (size_t)p * KD + k + 4);
    }
    o[0]=f2bf(s0[0]); o[1]=f2bf(s0[1]); o[2]=f2bf(s0[2]); o[3]=f2bf(s0[3]);
    o[4]=f2bf(s1[0]); o[5]=f2bf(s1[1]); o[6]=f2bf(s1[2]); o[7]=f2bf(s1[3]);
  } else {
    o[0]=0; o[1]=0; o[2]=0; o[3]=0; o[4]=0; o[5]=0; o[6]=0; o[7]=0;
  }
  *(u16x8_t*)(wbf3 + (size_t)u * 8) = o;
}

// ---- main: BM=64 (4 waves x 16 rows), BK=128, N=144 (9 frags).
// A: direct global->reg (nontemporal), fp32->bf16 in regs.
// B: global_load_lds(16B) from pre-fragmented wbf3 into double-buffered LDS.
// One __syncthreads per BK step. s0 comes out of MFMA as acc[8].
__global__ __launch_bounds__(256, 2) void k_main(
    const float* __restrict__ x, const unsigned short* __restrict__ wbf3,
    float* __restrict__ out)
{
  __shared__ __align__(16) unsigned char lds[2 * 36864];   // 72 KB double buffer
  const int t = threadIdx.x;
  const int lane = t & 63;
  const int wv = t >> 6;
  const int g = lane >> 4;
  const int r15 = lane & 15;
  const size_t tile = (size_t)blockIdx.x * 64;

  const float* xrow = x + (tile + wv * 16 + r15) * KD + g * 8;

  f32x4_t acc[9];
  #pragma unroll
  for (int i = 0; i < 9; ++i) acc[i] = f32x4_t{0.f, 0.f, 0.f, 0.f};

  // stage one BK=128 tile (36 KB = 36 chunks of 1KB; 9 chunks per wave)
  auto STAGE = [&](int it, int bsel) {
    unsigned char* bp = lds + bsel * 36864 + wv * 9 * 1024;
    const unsigned short* gp = wbf3 + (size_t)it * 18432 + wv * 9 * 512 + lane * 8;
    #pragma unroll
    for (int i = 0; i < 9; ++i)
      __builtin_amdgcn_global_load_lds(
          (const __attribute__((address_space(1))) void*)(gp + i * 512),
          (__attribute__((address_space(3))) void*)(bp + i * 1024), 16, 0, 0);
  };
  auto XLOAD = [&](int it, f32x4_t* xv) {
    const float* p = xrow + it * 128;
    #pragma unroll
    for (int ss = 0; ss < 4; ++ss) {
      xv[2*ss]   = __builtin_nontemporal_load((const f32x4_t*)(p + ss * 32));
      xv[2*ss+1] = __builtin_nontemporal_load((const f32x4_t*)(p + ss * 32 + 4));
    }
  };
  auto COMPUTE = [&](int bsel, const f32x4_t* xv) {
    const unsigned char* bp = lds + bsel * 36864;
    #pragma unroll
    for (int ss = 0; ss < 4; ++ss) {
      union { u16x8_t u; bf16x8_t b; } af;
      f32x4_t x0 = xv[2*ss], x1 = xv[2*ss+1];
      af.u[0]=f2bf(x0[0]); af.u[1]=f2bf(x0[1]); af.u[2]=f2bf(x0[2]); af.u[3]=f2bf(x0[3]);
      af.u[4]=f2bf(x1[0]); af.u[5]=f2bf(x1[1]); af.u[6]=f2bf(x1[2]); af.u[7]=f2bf(x1[3]);
      #pragma unroll
      for (int nf = 0; nf < 9; ++nf) {
        bf16x8_t bfr = *(const bf16x8_t*)(bp + ((ss * 9 + nf) * 64 + lane) * 16);
        acc[nf] = __builtin_amdgcn_mfma_f32_16x16x32_bf16(af.b, bfr, acc[nf], 0, 0, 0);
      }
    }
  };

  f32x4_t xA[8], xB[8];
  STAGE(0, 0);
  XLOAD(0, xA);
  __syncthreads();

  for (int it = 0; it < 16; it += 2) {
    STAGE(it + 1, 1);
    XLOAD(it + 1, xB);
    COMPUTE(0, xA);
    __syncthreads();
    if (it + 2 < 16) { STAGE(it + 2, 0); XLOAD(it + 2, xA); }
    COMPUTE(1, xB);
    __syncthreads();
  }

  // epilogue: C col=lane&15, row=g*4+reg. a-frag nf pairs with b-frag nf+4.
  // acc[8][r] (col 128) = qkv+z fold, already at the writer lane (r15==0).
  #pragma unroll
  for (int r = 0; r < 4; ++r) {
    float v = 0.f;
    #pragma unroll
    for (int nf = 0; nf < 4; ++nf) {
      float av = acc[nf][r];
      float bv = acc[nf + 4][r];
      v += av / (1.f + __expf(-bv));          // a * sigmoid(b)
    }
    v += __shfl_xor(v, 1, 64);
    v += __shfl_xor(v, 2, 64);
    v += __shfl_xor(v, 4, 64);
    v += __shfl_xor(v, 8, 64);
    if (r15 == 0) out[tile + wv * 16 + g * 4 + r] = v + acc[8][r];
  }
}

extern "C" void kernel_launch(void* const* d_in, const int* in_sizes, int n_in,
                              void* d_out, int out_size, void* d_ws, size_t ws_size,
                              hipStream_t stream) {
  const float* x    = (const float*)d_in[0];
  const float* wqkv = (const float*)d_in[1];
  const float* wz   = (const float*)d_in[2];
  const float* wb   = (const float*)d_in[3];   // dict order: w_b before w_a
  const float* wa   = (const float*)d_in[4];
  float* out = (float*)d_out;

  float* partial = (float*)d_ws;                                    // 128*2048 f32 = 1 MB
  unsigned short* wbf3 = (unsigned short*)((char*)d_ws + (1 << 20)); // 576 KB pre-fragmented W

  k_prep1<<<128, 256, 0, stream>>>(wqkv, wz, partial);
  k_prep2<<<144, 256, 0, stream>>>(wb, wa, partial, wbf3);
  k_main<<<out_size / 64, 256, 0, stream>>>(x, wbf3, out);
}